// Round 1
// baseline (355.340 us; speedup 1.0000x reference)
//
#include <hip/hip_runtime.h>
#include <stdint.h>

#define BATCH  64
#define SEQ    2048
#define DIM    512
#define NFINE  16
#define MSPANS 512

// ---------------------------------------------------------------------------
// Kernel A: one block per batch row.
//  - zero this row's output slice (d_out is poisoned 0xAA by the harness)
//  - block-scan cumsum of (label == B) -> inclusive span id per token
//  - compact valid tokens ((B|I) && 0<=seg<MSPANS) into packed (s<<16|seg)
//    per-row list in workspace + per-row count
// ---------------------------------------------------------------------------
__global__ __launch_bounds__(256) void build_spans_kernel(
    const int* __restrict__ labels,
    const int* __restrict__ pB, const int* __restrict__ pI,
    int* __restrict__ count, uint32_t* __restrict__ list,
    float* __restrict__ out)
{
    const int row = blockIdx.x;
    const int tid = threadIdx.x;                 // 0..255
    const int Btag = *pB, Itag = *pI;

    // zero output slice for this row: 512*16 floats = 2048 float4
    float4* oz = (float4*)(out + (size_t)row * MSPANS * NFINE);
    #pragma unroll
    for (int k = 0; k < 8; ++k)
        oz[tid + k * 256] = make_float4(0.f, 0.f, 0.f, 0.f);

    // 8 labels per thread, vectorized
    const int4* lab4 = (const int4*)(labels + (size_t)row * SEQ);
    int4 a = lab4[tid * 2], b = lab4[tid * 2 + 1];
    int l[8] = {a.x, a.y, a.z, a.w, b.x, b.y, b.z, b.w};
    int cnt = 0;
    #pragma unroll
    for (int k = 0; k < 8; ++k) cnt += (l[k] == Btag);

    __shared__ int scan[256];
    __shared__ int lcount;
    if (tid == 0) lcount = 0;
    scan[tid] = cnt;
    __syncthreads();
    // Hillis-Steele inclusive scan over 256 partial counts
    for (int off = 1; off < 256; off <<= 1) {
        int v = scan[tid];
        int u = (tid >= off) ? scan[tid - off] : 0;
        __syncthreads();
        scan[tid] = v + u;
        __syncthreads();
    }
    int run = (tid > 0) ? scan[tid - 1] : 0;     // exclusive prefix of B-count

    uint32_t* lrow = list + (size_t)row * SEQ;
    #pragma unroll
    for (int k = 0; k < 8; ++k) {
        const int  s   = tid * 8 + k;
        const bool isb = (l[k] == Btag);
        const bool isi = (l[k] == Itag);
        run += isb;
        const int seg = run - 1;                 // inclusive cumsum - 1
        if ((isb | isi) && seg >= 0 && seg < MSPANS) {
            int slot = atomicAdd(&lcount, 1);
            lrow[slot] = ((uint32_t)s << 16) | (uint32_t)seg;
        }
    }
    __syncthreads();
    if (tid == 0) count[row] = lcount;
}

// ---------------------------------------------------------------------------
// Kernel B: grid = 64 rows x 16 chunks, 256 threads (4 waves).
// Lane layout per wave: t = lane>>4 (token within group of 4), f = lane&15.
// sT[16][516] LDS holds slot_embs transposed (stride 516 words -> max 2-way
// bank aliasing, free). Per group: 16 f-lanes broadcast-load the token's
// hidden row float4-by-float4; each lane dots against its own sT[f] slice;
// one f32 atomicAdd per (token,f) into the output.
// ---------------------------------------------------------------------------
__global__ __launch_bounds__(256) void span_score_kernel(
    const float* __restrict__ hidden,
    const float* __restrict__ semb,
    const int* __restrict__ count,
    const uint32_t* __restrict__ list,
    float* __restrict__ out)
{
    __shared__ float sT[NFINE][DIM + 4];         // stride 516: 2-way max

    for (int i = threadIdx.x; i < DIM * NFINE; i += 256)
        sT[i & 15][i >> 4] = semb[i];            // semb is [d][f]
    __syncthreads();

    const int row   = blockIdx.x >> 4;
    const int chunk = blockIdx.x & 15;
    const int wave  = threadIdx.x >> 6;
    const int lane  = threadIdx.x & 63;
    const int t = lane >> 4, f = lane & 15;

    const int n = count[row];
    const float*    hbase = hidden + (size_t)row * SEQ * DIM;
    float*          obase = out    + (size_t)row * MSPANS * NFINE;
    const uint32_t* lrow  = list   + (size_t)row * SEQ;
    const float4*   ev    = (const float4*)&sT[f][0];   // 16B-aligned (2064B row)

    // wave id within row: 0..63; each processes groups of 4 tokens, stride 256
    for (int base = (chunk * 4 + wave) * 4; base < n; base += 256) {
        const int idx = base + t;
        if (idx < n) {
            const uint32_t e = lrow[idx];
            const int s   = (int)(e >> 16);
            const int seg = (int)(e & 0xffff);
            const float4* h4 = (const float4*)(hbase + (size_t)s * DIM);
            float a0 = 0.f, a1 = 0.f, a2 = 0.f, a3 = 0.f;
            #pragma unroll 4
            for (int d4 = 0; d4 < DIM / 4; d4 += 2) {
                float4 h0 = h4[d4], h1 = h4[d4 + 1];
                float4 e0 = ev[d4], e1 = ev[d4 + 1];
                a0 = fmaf(h0.x, e0.x, a0);
                a1 = fmaf(h0.y, e0.y, a1);
                a2 = fmaf(h0.z, e0.z, a2);
                a3 = fmaf(h0.w, e0.w, a3);
                a0 = fmaf(h1.x, e1.x, a0);
                a1 = fmaf(h1.y, e1.y, a1);
                a2 = fmaf(h1.z, e1.z, a2);
                a3 = fmaf(h1.w, e1.w, a3);
            }
            const float acc = (a0 + a1) + (a2 + a3);
            atomicAdd(obase + seg * NFINE + f, acc);
        }
    }
}

extern "C" void kernel_launch(void* const* d_in, const int* in_sizes, int n_in,
                              void* d_out, int out_size, void* d_ws, size_t ws_size,
                              hipStream_t stream)
{
    const float* hidden = (const float*)d_in[0];
    const float* semb   = (const float*)d_in[1];
    const int*   labels = (const int*)d_in[2];
    const int*   pB     = (const int*)d_in[3];
    const int*   pI     = (const int*)d_in[4];
    float* out = (float*)d_out;

    // ws layout: [0,256) row counts (64 ints), [256, 256+64*2048*4) packed lists
    int*      count = (int*)d_ws;
    uint32_t* list  = (uint32_t*)((char*)d_ws + 256);

    build_spans_kernel<<<BATCH, 256, 0, stream>>>(labels, pB, pI, count, list, out);
    span_score_kernel<<<BATCH * 16, 256, 0, stream>>>(hidden, semb, count, list, out);
}